// Round 1
// baseline (1098.313 us; speedup 1.0000x reference)
//
#include <hip/hip_runtime.h>
#include <math.h>

#define LRELU 0.2f

constexpr int Bn = 32, Sn = 512, Hn = 768, Nn = 4096, En = 131072, Pn = 65536;
constexpr int ET = En + Nn;  // edges + self loops

// ---------- workspace layout (float offsets) ----------
constexpr size_t OFF_X0  = 0;                      // 4096*768 = 3145728; later reused as ner_hid (16384*256 = 4194304)
constexpr size_t OFF_H1  = 4194304;                // 4096*512
constexpr size_t OFF_X1  = OFF_H1  + 2097152;      // 4096*512
constexpr size_t OFF_H2  = OFF_X1  + 2097152;      // 4096*64
constexpr size_t OFF_X2  = OFF_H2  + 262144;       // 4096*64
constexpr size_t OFF_ES1 = OFF_X2  + 262144;       // 4096*4
constexpr size_t OFF_ED1 = OFF_ES1 + 16384;
constexpr size_t OFF_ES2 = OFF_ED1 + 16384;        // 4096
constexpr size_t OFF_ED2 = OFF_ES2 + 4096;
constexpr size_t OFF_ROW = OFF_ED2 + 4096;         // int[4097]
constexpr size_t OFF_CUR = OFF_ROW + 4104;         // int[4096] (counts, then cursors)
constexpr size_t OFF_EDG = OFF_CUR + 4096;         // int[135168] sources sorted by dst
// end ~ 9.10M floats ~= 35 MB

// ---------------- span mean pooling ----------------
__global__ __launch_bounds__(256) void span_pool_k(
    const float* __restrict__ seq, const int* __restrict__ est,
    const int* __restrict__ eln, const int* __restrict__ ebt,
    float* __restrict__ x0) {
  int idx = blockIdx.x * 256 + threadIdx.x;
  if (idx >= Nn * (Hn / 4)) return;
  int e = idx / (Hn / 4);
  int c = (idx % (Hn / 4)) * 4;
  int s0 = est[e], L = eln[e] + 1, b = ebt[e];
  const float* p = seq + ((size_t)b * Sn + s0) * Hn + c;
  float ax = 0, ay = 0, az = 0, aw = 0;
  for (int i = 0; i < L; ++i) {
    float4 v = *(const float4*)(p + (size_t)i * Hn);
    ax += v.x; ay += v.y; az += v.z; aw += v.w;
  }
  float inv = 1.0f / (float)L;
  float4 o; o.x = ax * inv; o.y = ay * inv; o.z = az * inv; o.w = aw * inv;
  *(float4*)&x0[(size_t)e * Hn + c] = o;
}

// ---------------- generic fp32 tiled GEMM: C[M,Nc] = A[M,K] @ B[K,Nc] ----------------
// NT = col-tile (multiple of 4), thread covers RT rows x 4 cols. EPI: 0=none, 1=+bias,relu
template <int NT, int RT, int EPI>
__global__ __launch_bounds__(256) void gemm_k(
    const float* __restrict__ A, const float* __restrict__ Bm,
    float* __restrict__ Cm, const float* __restrict__ bias,
    int M, int K, int Nc) {
  constexpr int CT = NT / 4;       // col threads
  constexpr int RG = 256 / CT;     // row groups
  constexpr int MT = RG * RT;      // rows per block
  constexpr int KC = 64, KP = KC + 4;
  __shared__ float at[MT * KP];
  int t = threadIdx.x;
  int cg = t % CT, rg = t / CT;
  int colb = blockIdx.y * NT + 4 * cg;
  size_t rowb = (size_t)blockIdx.x * MT;
  float acc[RT][4];
#pragma unroll
  for (int i = 0; i < RT; ++i)
#pragma unroll
    for (int j = 0; j < 4; ++j) acc[i][j] = 0.f;

  for (int k0 = 0; k0 < K; k0 += KC) {
    constexpr int CH = MT * KC / 4 / 256;  // float4 loads per thread
#pragma unroll
    for (int i = 0; i < CH; ++i) {
      int cid = t + i * 256;
      int r = cid / (KC / 4);
      int c4 = (cid % (KC / 4)) * 4;
      *(float4*)&at[r * KP + c4] = *(const float4*)&A[(rowb + r) * K + k0 + c4];
    }
    __syncthreads();
#pragma unroll
    for (int f = 0; f < KC; f += 4) {
      float wl[4][4];
#pragma unroll
      for (int ff = 0; ff < 4; ++ff) {
        float4 w = *(const float4*)&Bm[(size_t)(k0 + f + ff) * Nc + colb];
        wl[ff][0] = w.x; wl[ff][1] = w.y; wl[ff][2] = w.z; wl[ff][3] = w.w;
      }
#pragma unroll
      for (int i = 0; i < RT; ++i) {
        float4 av = *(const float4*)&at[(rg * RT + i) * KP + f];
        float a0 = av.x, a1 = av.y, a2 = av.z, a3 = av.w;
#pragma unroll
        for (int j = 0; j < 4; ++j) {
          acc[i][j] += a0 * wl[0][j];
          acc[i][j] += a1 * wl[1][j];
          acc[i][j] += a2 * wl[2][j];
          acc[i][j] += a3 * wl[3][j];
        }
      }
    }
    __syncthreads();
  }
#pragma unroll
  for (int i = 0; i < RT; ++i) {
    size_t row = rowb + rg * RT + i;
    float b0 = 0, b1v = 0, b2v = 0, b3v = 0;
    if (EPI == 1) {
      float4 bv = *(const float4*)&bias[colb];
      b0 = bv.x; b1v = bv.y; b2v = bv.z; b3v = bv.w;
    }
    float4 o;
    o.x = acc[i][0] + b0; o.y = acc[i][1] + b1v;
    o.z = acc[i][2] + b2v; o.w = acc[i][3] + b3v;
    if (EPI == 1) {
      o.x = fmaxf(o.x, 0.f); o.y = fmaxf(o.y, 0.f);
      o.z = fmaxf(o.z, 0.f); o.w = fmaxf(o.w, 0.f);
    }
    *(float4*)&Cm[row * Nc + colb] = o;
  }
}

// ---------------- attention coefficients: e_src/e_dst [N,HD] ----------------
template <int HD, int C>
__global__ __launch_bounds__(256) void coef_k(
    const float* __restrict__ h, const float* __restrict__ a_src,
    const float* __restrict__ a_dst, float* __restrict__ es, float* __restrict__ ed) {
  int idx = blockIdx.x * 256 + threadIdx.x;
  if (idx >= Nn * HD) return;
  int n = idx / HD, hd = idx % HD;
  const float* hp = h + (size_t)n * HD * C + hd * C;
  const float* sp = a_src + hd * C;
  const float* dp = a_dst + hd * C;
  float s = 0, d = 0;
  for (int c = 0; c < C; c += 4) {
    float4 v = *(const float4*)(hp + c);
    float4 a = *(const float4*)(sp + c);
    float4 b = *(const float4*)(dp + c);
    s += v.x * a.x + v.y * a.y + v.z * a.z + v.w * a.w;
    d += v.x * b.x + v.y * b.y + v.z * b.z + v.w * b.w;
  }
  es[idx] = s; ed[idx] = d;
}

// ---------------- CSR build ----------------
__global__ void zero_k(int* __restrict__ p, int n) {
  int i = blockIdx.x * 256 + threadIdx.x;
  if (i < n) p[i] = 0;
}

__global__ void count_k(const int* __restrict__ eidx, int* __restrict__ cnt) {
  int i = blockIdx.x * 256 + threadIdx.x;
  if (i >= ET) return;
  int dst = (i < En) ? eidx[En + i] : (i - En);
  atomicAdd(&cnt[dst], 1);
}

// single block; reads counts from cnt_cur, writes exclusive offsets to rowoff[4097] and cnt_cur (cursors)
__global__ __launch_bounds__(256) void scan_k(int* cnt_cur, int* rowoff) {
  __shared__ int s[256];
  int t = threadIdx.x;
  int loc[16]; int run = 0; int base = t * 16;
#pragma unroll
  for (int i = 0; i < 16; ++i) { loc[i] = run; run += cnt_cur[base + i]; }
  s[t] = run;
  __syncthreads();
  for (int off = 1; off < 256; off <<= 1) {
    int v = (t >= off) ? s[t - off] : 0;
    __syncthreads();
    s[t] += v;
    __syncthreads();
  }
  int offset = (t > 0) ? s[t - 1] : 0;
#pragma unroll
  for (int i = 0; i < 16; ++i) {
    int o = offset + loc[i];
    rowoff[base + i] = o;
    cnt_cur[base + i] = o;
  }
  if (t == 255) rowoff[4096] = s[255];
}

__global__ void scatter_k(const int* __restrict__ eidx, int* __restrict__ cur,
                          int* __restrict__ esrc) {
  int i = blockIdx.x * 256 + threadIdx.x;
  if (i >= ET) return;
  int s, d;
  if (i < En) { s = eidx[i]; d = eidx[En + i]; } else { s = d = i - En; }
  int pos = atomicAdd(&cur[d], 1);
  esrc[pos] = s;
}

// ---------------- GAT softmax-aggregate, one block per dst node ----------------
template <int HD, int C, bool RELU>
__global__ __launch_bounds__(256) void gat_agg_k(
    const float* __restrict__ h, const float* __restrict__ es,
    const float* __restrict__ ed, const int* __restrict__ row_off,
    const int* __restrict__ eslist, const float* __restrict__ bias,
    float* __restrict__ xout) {
  constexpr int CAP = 320;
  __shared__ float red[256];
  __shared__ float mxs[HD], dns[HD];
  __shared__ float exc[CAP * HD];
  int n = blockIdx.x, t = threadIdx.x;
  int ro = row_off[n], deg = row_off[n + 1] - ro;
  int hd = t % HD, ei = t / HD;
  constexpr int ES = 256 / HD;
  float edv = ed[n * HD + hd];
  // pass 1: per-head max
  float pm = -3.402823466e38f;
  for (int j = ei; j < deg; j += ES) {
    int s = eslist[ro + j];
    float e = es[s * HD + hd] + edv;
    e = (e > 0.f) ? e : LRELU * e;
    pm = fmaxf(pm, e);
  }
  red[t] = pm;
  __syncthreads();
  for (int off = 128; off >= HD; off >>= 1) {
    if (t < off) red[t] = fmaxf(red[t], red[t + off]);
    __syncthreads();
  }
  if (t < HD) mxs[t] = red[t];
  __syncthreads();
  float mx = mxs[hd];
  // pass 2: exp-sum (+cache)
  float ps = 0.f;
  for (int j = ei; j < deg; j += ES) {
    int s = eslist[ro + j];
    float e = es[s * HD + hd] + edv;
    e = (e > 0.f) ? e : LRELU * e;
    float ex = __expf(e - mx);
    if (j < CAP) exc[j * HD + hd] = ex;
    ps += ex;
  }
  red[t] = ps;
  __syncthreads();
  for (int off = 128; off >= HD; off >>= 1) {
    if (t < off) red[t] += red[t + off];
    __syncthreads();
  }
  if (t < HD) dns[t] = red[t];
  __syncthreads();
  // pass 3: aggregate numerators, divide, bias, (relu)
  for (int c = t; c < HD * C; c += 256) {
    int hh = c / C;
    float mxh = mxs[hh], edh = ed[n * HD + hh];
    float acc = 0.f;
    for (int j = 0; j < deg; ++j) {
      int s = eslist[ro + j];
      float ex;
      if (j < CAP) ex = exc[j * HD + hh];
      else {
        float e = es[s * HD + hh] + edh;
        e = (e > 0.f) ? e : LRELU * e;
        ex = __expf(e - mxh);
      }
      acc += ex * h[(size_t)s * (HD * C) + c];
    }
    float v = acc / dns[hh] + bias[c];
    if (RELU) v = fmaxf(v, 0.f);
    xout[(size_t)n * (HD * C) + c] = v;
  }
}

// ---------------- relation head: gather pairs + GEMM(K=128) + bias + LN + relu + GEMV ----------------
// grid (P/64, 6); block 256. Wave rg owns 16 pair-rows x 256 cols (lane=col-group of 4).
__global__ __launch_bounds__(256) void rel_head_k(
    const float* __restrict__ x2, const int* __restrict__ pidx,
    const float* __restrict__ rW1, const float* __restrict__ rb1,
    const float* __restrict__ lng, const float* __restrict__ lnb,
    const float* __restrict__ rW2, const float* __restrict__ rb2,
    float* __restrict__ out) {
  __shared__ float feat[64 * 128];
  int t = threadIdx.x;
  int r = blockIdx.y;
  int pb = blockIdx.x * 64;
  // stage 64 pair rows of cat(x2[i0], x2[i1])
#pragma unroll
  for (int i = 0; i < 8; ++i) {
    int cid = t + i * 256;        // 0..2047 float4 chunks
    int p = cid >> 5, q = cid & 31;
    int half = q >> 4, off = (q & 15) * 4;
    int node = pidx[(pb + p) * 2 + half];
    *(float4*)&feat[cid * 4] = *(const float4*)&x2[(size_t)node * 64 + off];
  }
  __syncthreads();
  int cg = t & 63, rg = t >> 6;
  const float* Wb = rW1 + (size_t)r * 128 * 256 + 4 * cg;
  float acc[16][4];
#pragma unroll
  for (int i = 0; i < 16; ++i)
#pragma unroll
    for (int j = 0; j < 4; ++j) acc[i][j] = 0.f;
  for (int f = 0; f < 128; f += 4) {
    float wl[4][4];
#pragma unroll
    for (int ff = 0; ff < 4; ++ff) {
      float4 w = *(const float4*)&Wb[(size_t)(f + ff) * 256];
      wl[ff][0] = w.x; wl[ff][1] = w.y; wl[ff][2] = w.z; wl[ff][3] = w.w;
    }
#pragma unroll
    for (int i = 0; i < 16; ++i) {
      float4 av = *(const float4*)&feat[(rg * 16 + i) * 128 + f];
      float a0 = av.x, a1 = av.y, a2 = av.z, a3 = av.w;
#pragma unroll
      for (int j = 0; j < 4; ++j) {
        acc[i][j] += a0 * wl[0][j];
        acc[i][j] += a1 * wl[1][j];
        acc[i][j] += a2 * wl[2][j];
        acc[i][j] += a3 * wl[3][j];
      }
    }
  }
  // epilogue: +bias, LN over 256 (intra-wave), relu, dot with rW2
  float4 rbv = *(const float4*)&rb1[r * 256 + 4 * cg];
  float4 g4 = *(const float4*)&lng[r * 256 + 4 * cg];
  float4 b4 = *(const float4*)&lnb[r * 256 + 4 * cg];
  float4 w24 = *(const float4*)&rW2[r * 256 + 4 * cg];
  float gv[4] = {g4.x, g4.y, g4.z, g4.w};
  float bv[4] = {b4.x, b4.y, b4.z, b4.w};
  float wv[4] = {w24.x, w24.y, w24.z, w24.w};
  float rbl[4] = {rbv.x, rbv.y, rbv.z, rbv.w};
  float rb2v = rb2[r];
#pragma unroll
  for (int i = 0; i < 16; ++i) {
#pragma unroll
    for (int j = 0; j < 4; ++j) acc[i][j] += rbl[j];
    float s1 = acc[i][0] + acc[i][1] + acc[i][2] + acc[i][3];
    float s2 = acc[i][0] * acc[i][0] + acc[i][1] * acc[i][1] +
               acc[i][2] * acc[i][2] + acc[i][3] * acc[i][3];
#pragma unroll
    for (int off = 32; off >= 1; off >>= 1) {
      s1 += __shfl_xor(s1, off, 64);
      s2 += __shfl_xor(s2, off, 64);
    }
    float mu = s1 * (1.f / 256.f);
    float var = s2 * (1.f / 256.f) - mu * mu;
    float rs = rsqrtf(var + 1e-5f);
    float pv = 0.f;
#pragma unroll
    for (int j = 0; j < 4; ++j) {
      float v = (acc[i][j] - mu) * rs * gv[j] + bv[j];
      v = fmaxf(v, 0.f);
      pv += v * wv[j];
    }
#pragma unroll
    for (int off = 32; off >= 1; off >>= 1) pv += __shfl_xor(pv, off, 64);
    if (cg == i)
      out[(size_t)r * Pn + pb + rg * 16 + i] = pv + rb2v;
  }
}

// ---------------- NER second layer: out = hid @ W2[256,9] + b ----------------
__global__ __launch_bounds__(256) void ner2_k(
    const float* __restrict__ hid, const float* __restrict__ W2,
    const float* __restrict__ b2, float* __restrict__ out) {
  __shared__ float s[16 * 257];
  int t = threadIdx.x;
  int rowb = blockIdx.x * 16;
#pragma unroll
  for (int i = 0; i < 4; ++i) {
    int cid = t + i * 256;           // 1024 float4 chunks
    int r = cid >> 6;
    int c4 = (cid & 63) * 4;
    *(float4*)&s[r * 257 + c4] = *(const float4*)&hid[(size_t)(rowb + r) * 256 + c4];
  }
  __syncthreads();
  int r = t & 15, j = t >> 4;
  if (j < 9) {
    float a = 0.f;
    for (int k = 0; k < 256; ++k) a += s[r * 257 + k] * W2[k * 9 + j];
    out[(size_t)(rowb + r) * 9 + j] = a + b2[j];
  }
}

extern "C" void kernel_launch(void* const* d_in, const int* in_sizes, int n_in,
                              void* d_out, int out_size, void* d_ws, size_t ws_size,
                              hipStream_t stream) {
  const float* seq = (const float*)d_in[0];
  const int* est = (const int*)d_in[1];
  const int* eln = (const int*)d_in[2];
  const int* ebt = (const int*)d_in[3];
  const int* eidx = (const int*)d_in[4];
  const int* pidx = (const int*)d_in[5];
  const float* W1 = (const float*)d_in[6];
  const float* as1 = (const float*)d_in[7];
  const float* ad1 = (const float*)d_in[8];
  const float* b1 = (const float*)d_in[9];
  const float* W2 = (const float*)d_in[10];
  const float* as2 = (const float*)d_in[11];
  const float* ad2 = (const float*)d_in[12];
  const float* b2 = (const float*)d_in[13];
  const float* rW1 = (const float*)d_in[14];
  const float* rb1 = (const float*)d_in[15];
  const float* lng = (const float*)d_in[16];
  const float* lnb = (const float*)d_in[17];
  const float* rW2 = (const float*)d_in[18];
  const float* rb2 = (const float*)d_in[19];
  const float* nW1 = (const float*)d_in[20];
  const float* nb1 = (const float*)d_in[21];
  const float* nW2 = (const float*)d_in[22];
  const float* nb2 = (const float*)d_in[23];
  float* out = (float*)d_out;
  float* ws = (float*)d_ws;

  float* x0 = ws + OFF_X0;
  float* h1 = ws + OFF_H1;
  float* x1 = ws + OFF_X1;
  float* h2 = ws + OFF_H2;
  float* x2 = ws + OFF_X2;
  float* es1 = ws + OFF_ES1;
  float* ed1 = ws + OFF_ED1;
  float* es2 = ws + OFF_ES2;
  float* ed2 = ws + OFF_ED2;
  int* rowoff = (int*)(ws + OFF_ROW);
  int* cur = (int*)(ws + OFF_CUR);
  int* edg = (int*)(ws + OFF_EDG);
  float* nhid = ws + OFF_X0;  // reuse x0 region after GAT1 GEMM is done

  // CSR build (independent of features)
  zero_k<<<16, 256, 0, stream>>>(cur, Nn);
  count_k<<<(ET + 255) / 256, 256, 0, stream>>>(eidx, cur);
  scan_k<<<1, 256, 0, stream>>>(cur, rowoff);
  scatter_k<<<(ET + 255) / 256, 256, 0, stream>>>(eidx, cur, edg);

  // entity features
  span_pool_k<<<Nn * (Hn / 4) / 256, 256, 0, stream>>>(seq, est, eln, ebt, x0);

  // GAT layer 1
  gemm_k<256, 16, 0><<<dim3(Nn / 64, 512 / 256), 256, 0, stream>>>(x0, W1, h1, nullptr, Nn, Hn, 512);
  coef_k<4, 128><<<(Nn * 4) / 256, 256, 0, stream>>>(h1, as1, ad1, es1, ed1);
  gat_agg_k<4, 128, true><<<Nn, 256, 0, stream>>>(h1, es1, ed1, rowoff, edg, b1, x1);

  // GAT layer 2
  gemm_k<64, 4, 0><<<dim3(Nn / 64, 1), 256, 0, stream>>>(x1, W2, h2, nullptr, Nn, 512, 64);
  coef_k<1, 64><<<(Nn + 255) / 256, 256, 0, stream>>>(h2, as2, ad2, es2, ed2);
  gat_agg_k<1, 64, false><<<Nn, 256, 0, stream>>>(h2, es2, ed2, rowoff, edg, b2, x2);

  // relation head -> out[147456 ..]
  rel_head_k<<<dim3(Pn / 64, 6), 256, 0, stream>>>(x2, pidx, rW1, rb1, lng, lnb, rW2, rb2,
                                                   out + (size_t)Bn * Sn * 9);

  // NER head -> out[0 .. 147455] (x0 region is dead now; reuse as hid)
  gemm_k<256, 16, 1><<<dim3((Bn * Sn) / 64, 1), 256, 0, stream>>>(seq, nW1, nhid, nb1, Bn * Sn, Hn, 256);
  ner2_k<<<(Bn * Sn) / 16, 256, 0, stream>>>(nhid, nW2, nb2, out);
}

// Round 2
// 874.838 us; speedup vs baseline: 1.2554x; 1.2554x over previous
//
#include <hip/hip_runtime.h>
#include <math.h>

#define LRELU 0.2f

constexpr int Bn = 32, Sn = 512, Hn = 768, Nn = 4096, En = 131072, Pn = 65536;
constexpr int ET = En + Nn;  // edges + self loops

typedef __attribute__((ext_vector_type(8))) short bf16x8;
typedef __attribute__((ext_vector_type(4))) float f32x4;

// ---------- workspace layout (float offsets) ----------
constexpr size_t OFF_X0  = 0;                      // 4096*768; later reused as ner_hid (16384*256)
constexpr size_t OFF_X2B = 3145728;                // 4096*64 bf16 -> 131072 float slots (gap before nhid end)
constexpr size_t OFF_BSW = OFF_X2B + 131072;       // 6*128*256 bf16 swizzled -> 98304 float slots (ends 3375104 < 4194304)
constexpr size_t OFF_H1  = 4194304;                // 4096*512
constexpr size_t OFF_X1  = OFF_H1  + 2097152;      // 4096*512
constexpr size_t OFF_H2  = OFF_X1  + 2097152;      // 4096*64
constexpr size_t OFF_X2  = OFF_H2  + 262144;       // 4096*64
constexpr size_t OFF_ES1 = OFF_X2  + 262144;       // 4096*4
constexpr size_t OFF_ED1 = OFF_ES1 + 16384;
constexpr size_t OFF_ES2 = OFF_ED1 + 16384;        // 4096
constexpr size_t OFF_ED2 = OFF_ES2 + 4096;
constexpr size_t OFF_ROW = OFF_ED2 + 4096;         // int[4097]
constexpr size_t OFF_CUR = OFF_ROW + 4104;         // int[4096]
constexpr size_t OFF_EDG = OFF_CUR + 4096;         // int[135168]

__device__ __forceinline__ short f2bf(float f) {
  union { float f; unsigned u; } x; x.f = f;
  unsigned r = x.u + 0x7fff + ((x.u >> 16) & 1);   // RNE
  return (short)(r >> 16);
}

// ---------------- span mean pooling ----------------
__global__ __launch_bounds__(256) void span_pool_k(
    const float* __restrict__ seq, const int* __restrict__ est,
    const int* __restrict__ eln, const int* __restrict__ ebt,
    float* __restrict__ x0) {
  int idx = blockIdx.x * 256 + threadIdx.x;
  if (idx >= Nn * (Hn / 4)) return;
  int e = idx / (Hn / 4);
  int c = (idx % (Hn / 4)) * 4;
  int s0 = est[e], L = eln[e] + 1, b = ebt[e];
  const float* p = seq + ((size_t)b * Sn + s0) * Hn + c;
  float ax = 0, ay = 0, az = 0, aw = 0;
  for (int i = 0; i < L; ++i) {
    float4 v = *(const float4*)(p + (size_t)i * Hn);
    ax += v.x; ay += v.y; az += v.z; aw += v.w;
  }
  float inv = 1.0f / (float)L;
  float4 o; o.x = ax * inv; o.y = ay * inv; o.z = az * inv; o.w = aw * inv;
  *(float4*)&x0[(size_t)e * Hn + c] = o;
}

// ---------------- generic fp32 tiled GEMM ----------------
template <int NT, int RT, int EPI>
__global__ __launch_bounds__(256) void gemm_k(
    const float* __restrict__ A, const float* __restrict__ Bm,
    float* __restrict__ Cm, const float* __restrict__ bias,
    int M, int K, int Nc) {
  constexpr int CT = NT / 4;
  constexpr int RG = 256 / CT;
  constexpr int MT = RG * RT;
  constexpr int KC = 64, KP = KC + 4;
  __shared__ float at[MT * KP];
  int t = threadIdx.x;
  int cg = t % CT, rg = t / CT;
  int colb = blockIdx.y * NT + 4 * cg;
  size_t rowb = (size_t)blockIdx.x * MT;
  float acc[RT][4];
#pragma unroll
  for (int i = 0; i < RT; ++i)
#pragma unroll
    for (int j = 0; j < 4; ++j) acc[i][j] = 0.f;

  for (int k0 = 0; k0 < K; k0 += KC) {
    constexpr int CH = MT * KC / 4 / 256;
#pragma unroll
    for (int i = 0; i < CH; ++i) {
      int cid = t + i * 256;
      int r = cid / (KC / 4);
      int c4 = (cid % (KC / 4)) * 4;
      *(float4*)&at[r * KP + c4] = *(const float4*)&A[(rowb + r) * K + k0 + c4];
    }
    __syncthreads();
#pragma unroll
    for (int f = 0; f < KC; f += 4) {
      float wl[4][4];
#pragma unroll
      for (int ff = 0; ff < 4; ++ff) {
        float4 w = *(const float4*)&Bm[(size_t)(k0 + f + ff) * Nc + colb];
        wl[ff][0] = w.x; wl[ff][1] = w.y; wl[ff][2] = w.z; wl[ff][3] = w.w;
      }
#pragma unroll
      for (int i = 0; i < RT; ++i) {
        float4 av = *(const float4*)&at[(rg * RT + i) * KP + f];
        float a0 = av.x, a1 = av.y, a2 = av.z, a3 = av.w;
#pragma unroll
        for (int j = 0; j < 4; ++j) {
          acc[i][j] += a0 * wl[0][j];
          acc[i][j] += a1 * wl[1][j];
          acc[i][j] += a2 * wl[2][j];
          acc[i][j] += a3 * wl[3][j];
        }
      }
    }
    __syncthreads();
  }
#pragma unroll
  for (int i = 0; i < RT; ++i) {
    size_t row = rowb + rg * RT + i;
    float b0 = 0, b1v = 0, b2v = 0, b3v = 0;
    if (EPI == 1) {
      float4 bv = *(const float4*)&bias[colb];
      b0 = bv.x; b1v = bv.y; b2v = bv.z; b3v = bv.w;
    }
    float4 o;
    o.x = acc[i][0] + b0; o.y = acc[i][1] + b1v;
    o.z = acc[i][2] + b2v; o.w = acc[i][3] + b3v;
    if (EPI == 1) {
      o.x = fmaxf(o.x, 0.f); o.y = fmaxf(o.y, 0.f);
      o.z = fmaxf(o.z, 0.f); o.w = fmaxf(o.w, 0.f);
    }
    *(float4*)&Cm[row * Nc + colb] = o;
  }
}

// ---------------- attention coefficients ----------------
template <int HD, int C>
__global__ __launch_bounds__(256) void coef_k(
    const float* __restrict__ h, const float* __restrict__ a_src,
    const float* __restrict__ a_dst, float* __restrict__ es, float* __restrict__ ed) {
  int idx = blockIdx.x * 256 + threadIdx.x;
  if (idx >= Nn * HD) return;
  int n = idx / HD, hd = idx % HD;
  const float* hp = h + (size_t)n * HD * C + hd * C;
  const float* sp = a_src + hd * C;
  const float* dp = a_dst + hd * C;
  float s = 0, d = 0;
  for (int c = 0; c < C; c += 4) {
    float4 v = *(const float4*)(hp + c);
    float4 a = *(const float4*)(sp + c);
    float4 b = *(const float4*)(dp + c);
    s += v.x * a.x + v.y * a.y + v.z * a.z + v.w * a.w;
    d += v.x * b.x + v.y * b.y + v.z * b.z + v.w * b.w;
  }
  es[idx] = s; ed[idx] = d;
}

// ---------------- CSR build ----------------
__global__ void zero_k(int* __restrict__ p, int n) {
  int i = blockIdx.x * 256 + threadIdx.x;
  if (i < n) p[i] = 0;
}

__global__ void count_k(const int* __restrict__ eidx, int* __restrict__ cnt) {
  int i = blockIdx.x * 256 + threadIdx.x;
  if (i >= ET) return;
  int dst = (i < En) ? eidx[En + i] : (i - En);
  atomicAdd(&cnt[dst], 1);
}

__global__ __launch_bounds__(256) void scan_k(int* cnt_cur, int* rowoff) {
  __shared__ int s[256];
  int t = threadIdx.x;
  int loc[16]; int run = 0; int base = t * 16;
#pragma unroll
  for (int i = 0; i < 16; ++i) { loc[i] = run; run += cnt_cur[base + i]; }
  s[t] = run;
  __syncthreads();
  for (int off = 1; off < 256; off <<= 1) {
    int v = (t >= off) ? s[t - off] : 0;
    __syncthreads();
    s[t] += v;
    __syncthreads();
  }
  int offset = (t > 0) ? s[t - 1] : 0;
#pragma unroll
  for (int i = 0; i < 16; ++i) {
    int o = offset + loc[i];
    rowoff[base + i] = o;
    cnt_cur[base + i] = o;
  }
  if (t == 255) rowoff[4096] = s[255];
}

__global__ void scatter_k(const int* __restrict__ eidx, int* __restrict__ cur,
                          int* __restrict__ esrc) {
  int i = blockIdx.x * 256 + threadIdx.x;
  if (i >= ET) return;
  int s, d;
  if (i < En) { s = eidx[i]; d = eidx[En + i]; } else { s = d = i - En; }
  int pos = atomicAdd(&cur[d], 1);
  esrc[pos] = s;
}

// ---------------- GAT softmax-aggregate ----------------
template <int HD, int C, bool RELU>
__global__ __launch_bounds__(256) void gat_agg_k(
    const float* __restrict__ h, const float* __restrict__ es,
    const float* __restrict__ ed, const int* __restrict__ row_off,
    const int* __restrict__ eslist, const float* __restrict__ bias,
    float* __restrict__ xout) {
  constexpr int CAP = 320;
  __shared__ float red[256];
  __shared__ float mxs[HD], dns[HD];
  __shared__ float exc[CAP * HD];
  int n = blockIdx.x, t = threadIdx.x;
  int ro = row_off[n], deg = row_off[n + 1] - ro;
  int hd = t % HD, ei = t / HD;
  constexpr int ES = 256 / HD;
  float edv = ed[n * HD + hd];
  float pm = -3.402823466e38f;
  for (int j = ei; j < deg; j += ES) {
    int s = eslist[ro + j];
    float e = es[s * HD + hd] + edv;
    e = (e > 0.f) ? e : LRELU * e;
    pm = fmaxf(pm, e);
  }
  red[t] = pm;
  __syncthreads();
  for (int off = 128; off >= HD; off >>= 1) {
    if (t < off) red[t] = fmaxf(red[t], red[t + off]);
    __syncthreads();
  }
  if (t < HD) mxs[t] = red[t];
  __syncthreads();
  float mx = mxs[hd];
  float ps = 0.f;
  for (int j = ei; j < deg; j += ES) {
    int s = eslist[ro + j];
    float e = es[s * HD + hd] + edv;
    e = (e > 0.f) ? e : LRELU * e;
    float ex = __expf(e - mx);
    if (j < CAP) exc[j * HD + hd] = ex;
    ps += ex;
  }
  red[t] = ps;
  __syncthreads();
  for (int off = 128; off >= HD; off >>= 1) {
    if (t < off) red[t] += red[t + off];
    __syncthreads();
  }
  if (t < HD) dns[t] = red[t];
  __syncthreads();
  for (int c = t; c < HD * C; c += 256) {
    int hh = c / C;
    float mxh = mxs[hh], edh = ed[n * HD + hh];
    float acc = 0.f;
    for (int j = 0; j < deg; ++j) {
      int s = eslist[ro + j];
      float ex;
      if (j < CAP) ex = exc[j * HD + hh];
      else {
        float e = es[s * HD + hh] + edh;
        e = (e > 0.f) ? e : LRELU * e;
        ex = __expf(e - mxh);
      }
      acc += ex * h[(size_t)s * (HD * C) + c];
    }
    float v = acc / dns[hh] + bias[c];
    if (RELU) v = fmaxf(v, 0.f);
    xout[(size_t)n * (HD * C) + c] = v;
  }
}

// ---------------- bf16 prep kernels ----------------
__global__ void cvt_x2_k(const float* __restrict__ x2, short* __restrict__ x2b) {
  int i = blockIdx.x * 256 + threadIdx.x;
  if (i < Nn * 64) x2b[i] = f2bf(x2[i]);
}

// swizzle rW1[r][k][n] -> Bswz[((r*4+kk)*16+ntg)*512 + lane*8 + j]
// kk=k>>5, lane = ((k>>3)&3)*16 + (n&15), j=k&7, ntg=n>>4
__global__ void swz_w1_k(const float* __restrict__ rW1, short* __restrict__ Bswz) {
  int i = blockIdx.x * 256 + threadIdx.x;
  if (i >= 6 * 128 * 256) return;
  int n = i & 255, k = (i >> 8) & 127, r = i >> 15;
  int kk = k >> 5, kq = (k >> 3) & 3, j = k & 7, ntg = n >> 4, id = n & 15;
  size_t dst = (((size_t)r * 4 + kk) * 16 + ntg) * 512 + (kq * 16 + id) * 8 + j;
  Bswz[dst] = f2bf(rW1[i]);
}

// ---------------- relation head: MFMA bf16 ----------------
// grid (P/64, 6); block 256 = 4 waves. Wave w: 64 rows x cols [w*64, w*64+64).
__global__ __launch_bounds__(256) void rel_head_mfma_k(
    const short* __restrict__ x2b, const int* __restrict__ pidx,
    const short* __restrict__ Bswz, const float* __restrict__ rb1,
    const float* __restrict__ lng, const float* __restrict__ lnb,
    const float* __restrict__ rW2, const float* __restrict__ rb2,
    float* __restrict__ out) {
  constexpr int RS = 136;                 // padded row stride (shorts); 272B = 17*16
  __shared__ short feat[64 * RS];         // 17.4 KB
  __shared__ float part[64 * 8];          // per-row partials (s1|s2 or dot), per wave
  __shared__ float stats[64 * 2];         // mu, rs
  int t = threadIdx.x;
  int r = blockIdx.y;
  int pb = blockIdx.x * 64;
  // stage 64 pair rows of cat(x2b[i0], x2b[i1]) as bf16
#pragma unroll
  for (int i = 0; i < 4; ++i) {
    int cid = t + i * 256;                // 1024 chunks of 8 bf16
    int p = cid >> 4, q = cid & 15;
    int half = q >> 3, o8 = (q & 7) * 8;
    int node = pidx[(pb + p) * 2 + half];
    *(bf16x8*)&feat[p * RS + half * 64 + o8] = *(const bf16x8*)&x2b[(size_t)node * 64 + o8];
  }
  __syncthreads();

  int w = t >> 6, lane = t & 63;
  int quad = lane >> 4, id = lane & 15;
  f32x4 acc[4][4];
#pragma unroll
  for (int mt = 0; mt < 4; ++mt)
#pragma unroll
    for (int nt = 0; nt < 4; ++nt) acc[mt][nt] = (f32x4){0.f, 0.f, 0.f, 0.f};

  const short* Bb = Bswz + (size_t)r * 4 * 16 * 512;
#pragma unroll
  for (int kk = 0; kk < 4; ++kk) {
    bf16x8 af[4], bfr[4];
#pragma unroll
    for (int mt = 0; mt < 4; ++mt)
      af[mt] = *(const bf16x8*)&feat[(mt * 16 + id) * RS + kk * 32 + quad * 8];
#pragma unroll
    for (int nt = 0; nt < 4; ++nt)
      bfr[nt] = *(const bf16x8*)&Bb[((size_t)kk * 16 + w * 4 + nt) * 512 + lane * 8];
#pragma unroll
    for (int mt = 0; mt < 4; ++mt)
#pragma unroll
      for (int nt = 0; nt < 4; ++nt)
        acc[mt][nt] = __builtin_amdgcn_mfma_f32_16x16x32_bf16(af[mt], bfr[nt], acc[mt][nt], 0, 0, 0);
  }

  // epilogue constants for this lane's 4 columns (col = w*64 + nt*16 + id)
  float g[4], bv[4], w2[4], rbl[4];
#pragma unroll
  for (int nt = 0; nt < 4; ++nt) {
    int c = r * 256 + w * 64 + nt * 16 + id;
    g[nt] = lng[c]; bv[nt] = lnb[c]; w2[nt] = rW2[c]; rbl[nt] = rb1[c];
  }
  // bias add + per-row (s1,s2) partials over this wave's 64 cols
#pragma unroll
  for (int mt = 0; mt < 4; ++mt) {
#pragma unroll
    for (int reg = 0; reg < 4; ++reg) {
      float s1 = 0.f, s2 = 0.f;
#pragma unroll
      for (int nt = 0; nt < 4; ++nt) {
        float v = acc[mt][nt][reg] + rbl[nt];
        acc[mt][nt][reg] = v;
        s1 += v; s2 += v * v;
      }
#pragma unroll
      for (int off = 1; off < 16; off <<= 1) {
        s1 += __shfl_xor(s1, off, 64);
        s2 += __shfl_xor(s2, off, 64);
      }
      if (id == 0) {
        int row = mt * 16 + quad * 4 + reg;
        part[row * 8 + w] = s1;
        part[row * 8 + 4 + w] = s2;
      }
    }
  }
  __syncthreads();
  if (t < 64) {
    float s1 = part[t * 8 + 0] + part[t * 8 + 1] + part[t * 8 + 2] + part[t * 8 + 3];
    float s2 = part[t * 8 + 4] + part[t * 8 + 5] + part[t * 8 + 6] + part[t * 8 + 7];
    float mu = s1 * (1.f / 256.f);
    float var = s2 * (1.f / 256.f) - mu * mu;
    stats[t * 2] = mu;
    stats[t * 2 + 1] = rsqrtf(var + 1e-5f);
  }
  __syncthreads();
  // LN + relu + dot(w2) partials
#pragma unroll
  for (int mt = 0; mt < 4; ++mt) {
#pragma unroll
    for (int reg = 0; reg < 4; ++reg) {
      int row = mt * 16 + quad * 4 + reg;
      float mu = stats[row * 2], rs = stats[row * 2 + 1];
      float pv = 0.f;
#pragma unroll
      for (int nt = 0; nt < 4; ++nt) {
        float v = (acc[mt][nt][reg] - mu) * rs * g[nt] + bv[nt];
        v = fmaxf(v, 0.f);
        pv += v * w2[nt];
      }
#pragma unroll
      for (int off = 1; off < 16; off <<= 1) pv += __shfl_xor(pv, off, 64);
      if (id == 0) part[row * 8 + w] = pv;
    }
  }
  __syncthreads();
  if (t < 64)
    out[(size_t)r * Pn + pb + t] =
        part[t * 8 + 0] + part[t * 8 + 1] + part[t * 8 + 2] + part[t * 8 + 3] + rb2[r];
}

// ---------------- NER second layer ----------------
__global__ __launch_bounds__(256) void ner2_k(
    const float* __restrict__ hid, const float* __restrict__ W2,
    const float* __restrict__ b2, float* __restrict__ out) {
  __shared__ float s[16 * 257];
  int t = threadIdx.x;
  int rowb = blockIdx.x * 16;
#pragma unroll
  for (int i = 0; i < 4; ++i) {
    int cid = t + i * 256;
    int r = cid >> 6;
    int c4 = (cid & 63) * 4;
    *(float4*)&s[r * 257 + c4] = *(const float4*)&hid[(size_t)(rowb + r) * 256 + c4];
  }
  __syncthreads();
  int r = t & 15, j = t >> 4;
  if (j < 9) {
    float a = 0.f;
    for (int k = 0; k < 256; ++k) a += s[r * 257 + k] * W2[k * 9 + j];
    out[(size_t)(rowb + r) * 9 + j] = a + b2[j];
  }
}

extern "C" void kernel_launch(void* const* d_in, const int* in_sizes, int n_in,
                              void* d_out, int out_size, void* d_ws, size_t ws_size,
                              hipStream_t stream) {
  const float* seq = (const float*)d_in[0];
  const int* est = (const int*)d_in[1];
  const int* eln = (const int*)d_in[2];
  const int* ebt = (const int*)d_in[3];
  const int* eidx = (const int*)d_in[4];
  const int* pidx = (const int*)d_in[5];
  const float* W1 = (const float*)d_in[6];
  const float* as1 = (const float*)d_in[7];
  const float* ad1 = (const float*)d_in[8];
  const float* b1 = (const float*)d_in[9];
  const float* W2 = (const float*)d_in[10];
  const float* as2 = (const float*)d_in[11];
  const float* ad2 = (const float*)d_in[12];
  const float* b2 = (const float*)d_in[13];
  const float* rW1 = (const float*)d_in[14];
  const float* rb1 = (const float*)d_in[15];
  const float* lng = (const float*)d_in[16];
  const float* lnb = (const float*)d_in[17];
  const float* rW2 = (const float*)d_in[18];
  const float* rb2 = (const float*)d_in[19];
  const float* nW1 = (const float*)d_in[20];
  const float* nb1 = (const float*)d_in[21];
  const float* nW2 = (const float*)d_in[22];
  const float* nb2 = (const float*)d_in[23];
  float* out = (float*)d_out;
  float* ws = (float*)d_ws;

  float* x0 = ws + OFF_X0;
  short* x2b = (short*)(ws + OFF_X2B);
  short* bsw = (short*)(ws + OFF_BSW);
  float* h1 = ws + OFF_H1;
  float* x1 = ws + OFF_X1;
  float* h2 = ws + OFF_H2;
  float* x2 = ws + OFF_X2;
  float* es1 = ws + OFF_ES1;
  float* ed1 = ws + OFF_ED1;
  float* es2 = ws + OFF_ES2;
  float* ed2 = ws + OFF_ED2;
  int* rowoff = (int*)(ws + OFF_ROW);
  int* cur = (int*)(ws + OFF_CUR);
  int* edg = (int*)(ws + OFF_EDG);
  float* nhid = ws + OFF_X0;  // reuse x0 region after GAT1 GEMM is done

  // CSR build + weight swizzle (independent of features)
  zero_k<<<16, 256, 0, stream>>>(cur, Nn);
  count_k<<<(ET + 255) / 256, 256, 0, stream>>>(eidx, cur);
  scan_k<<<1, 256, 0, stream>>>(cur, rowoff);
  scatter_k<<<(ET + 255) / 256, 256, 0, stream>>>(eidx, cur, edg);
  swz_w1_k<<<(6 * 128 * 256) / 256, 256, 0, stream>>>(rW1, bsw);

  // entity features
  span_pool_k<<<Nn * (Hn / 4) / 256, 256, 0, stream>>>(seq, est, eln, ebt, x0);

  // GAT layer 1
  gemm_k<256, 16, 0><<<dim3(Nn / 64, 512 / 256), 256, 0, stream>>>(x0, W1, h1, nullptr, Nn, Hn, 512);
  coef_k<4, 128><<<(Nn * 4) / 256, 256, 0, stream>>>(h1, as1, ad1, es1, ed1);
  gat_agg_k<4, 128, true><<<Nn, 256, 0, stream>>>(h1, es1, ed1, rowoff, edg, b1, x1);

  // GAT layer 2
  gemm_k<64, 4, 0><<<dim3(Nn / 64, 1), 256, 0, stream>>>(x1, W2, h2, nullptr, Nn, 512, 64);
  coef_k<1, 64><<<(Nn + 255) / 256, 256, 0, stream>>>(h2, as2, ad2, es2, ed2);
  gat_agg_k<1, 64, false><<<Nn, 256, 0, stream>>>(h2, es2, ed2, rowoff, edg, b2, x2);
  cvt_x2_k<<<(Nn * 64) / 256, 256, 0, stream>>>(x2, x2b);

  // relation head (MFMA bf16) -> out[147456 ..]
  rel_head_mfma_k<<<dim3(Pn / 64, 6), 256, 0, stream>>>(x2b, pidx, bsw, rb1, lng, lnb, rW2, rb2,
                                                        out + (size_t)Bn * Sn * 9);

  // NER head -> out[0 .. 147455]
  gemm_k<256, 16, 1><<<dim3((Bn * Sn) / 64, 1), 256, 0, stream>>>(seq, nW1, nhid, nb1, Bn * Sn, Hn, 256);
  ner2_k<<<(Bn * Sn) / 16, 256, 0, stream>>>(nhid, nW2, nb2, out);
}

// Round 3
// 510.074 us; speedup vs baseline: 2.1532x; 1.7151x over previous
//
#include <hip/hip_runtime.h>
#include <math.h>

#define LRELU 0.2f

constexpr int Bn = 32, Sn = 512, Hn = 768, Nn = 4096, En = 131072, Pn = 65536;
constexpr int ET = En + Nn;  // edges + self loops

typedef __attribute__((ext_vector_type(8))) short bf16x8;
typedef __attribute__((ext_vector_type(4))) float f32x4;

// ---------- workspace layout (float offsets) ----------
constexpr size_t OFF_X0  = 0;                      // 4096*768; later reused as ner_hid (16384*256)
constexpr size_t OFF_X2B = 3145728;                // 4096*64 bf16 (dies before nhid is written)
constexpr size_t OFF_BSW = OFF_X2B + 131072;       // rel-head swizzled weights (dies before nhid)
constexpr size_t OFF_H1  = 4194304;                // 4096*512
constexpr size_t OFF_X1  = OFF_H1  + 2097152;      // 4096*512
constexpr size_t OFF_H2  = OFF_X1  + 2097152;      // 4096*64
constexpr size_t OFF_X2  = OFF_H2  + 262144;       // 4096*64
constexpr size_t OFF_ES1 = OFF_X2  + 262144;       // 4096*4
constexpr size_t OFF_ED1 = OFF_ES1 + 16384;
constexpr size_t OFF_ES2 = OFF_ED1 + 16384;        // 4096
constexpr size_t OFF_ED2 = OFF_ES2 + 4096;
constexpr size_t OFF_ROW = OFF_ED2 + 4096;         // int[4097]
constexpr size_t OFF_CUR = OFF_ROW + 4104;         // int[4096]
constexpr size_t OFF_EDG = OFF_CUR + 4096;         // int[135168]
constexpr size_t OFF_W1S = OFF_EDG + 135168;       // 768*512 bf16 swizzled = 196608 floats
constexpr size_t OFF_NW1S = OFF_W1S + 196608;      // 768*256 bf16 swizzled = 98304 floats
// end ~ 9.40M floats ~= 37.6 MB

__device__ __forceinline__ short f2bf(float f) {
  union { float f; unsigned u; } x; x.f = f;
  unsigned r = x.u + 0x7fff + ((x.u >> 16) & 1);   // RNE
  return (short)(r >> 16);
}

// ---------------- span mean pooling ----------------
__global__ __launch_bounds__(256) void span_pool_k(
    const float* __restrict__ seq, const int* __restrict__ est,
    const int* __restrict__ eln, const int* __restrict__ ebt,
    float* __restrict__ x0) {
  int idx = blockIdx.x * 256 + threadIdx.x;
  if (idx >= Nn * (Hn / 4)) return;
  int e = idx / (Hn / 4);
  int c = (idx % (Hn / 4)) * 4;
  int s0 = est[e], L = eln[e] + 1, b = ebt[e];
  const float* p = seq + ((size_t)b * Sn + s0) * Hn + c;
  float ax = 0, ay = 0, az = 0, aw = 0;
  for (int i = 0; i < L; ++i) {
    float4 v = *(const float4*)(p + (size_t)i * Hn);
    ax += v.x; ay += v.y; az += v.z; aw += v.w;
  }
  float inv = 1.0f / (float)L;
  float4 o; o.x = ax * inv; o.y = ay * inv; o.z = az * inv; o.w = aw * inv;
  *(float4*)&x0[(size_t)e * Hn + c] = o;
}

// ---------------- fp32 tiled GEMM (only GAT2 now) ----------------
template <int NT, int RT, int EPI>
__global__ __launch_bounds__(256) void gemm_k(
    const float* __restrict__ A, const float* __restrict__ Bm,
    float* __restrict__ Cm, const float* __restrict__ bias,
    int M, int K, int Nc) {
  constexpr int CT = NT / 4;
  constexpr int RG = 256 / CT;
  constexpr int MT = RG * RT;
  constexpr int KC = 64, KP = KC + 4;
  __shared__ float at[MT * KP];
  int t = threadIdx.x;
  int cg = t % CT, rg = t / CT;
  int colb = blockIdx.y * NT + 4 * cg;
  size_t rowb = (size_t)blockIdx.x * MT;
  float acc[RT][4];
#pragma unroll
  for (int i = 0; i < RT; ++i)
#pragma unroll
    for (int j = 0; j < 4; ++j) acc[i][j] = 0.f;

  for (int k0 = 0; k0 < K; k0 += KC) {
    constexpr int CH = MT * KC / 4 / 256;
#pragma unroll
    for (int i = 0; i < CH; ++i) {
      int cid = t + i * 256;
      int r = cid / (KC / 4);
      int c4 = (cid % (KC / 4)) * 4;
      *(float4*)&at[r * KP + c4] = *(const float4*)&A[(rowb + r) * K + k0 + c4];
    }
    __syncthreads();
#pragma unroll
    for (int f = 0; f < KC; f += 4) {
      float wl[4][4];
#pragma unroll
      for (int ff = 0; ff < 4; ++ff) {
        float4 w = *(const float4*)&Bm[(size_t)(k0 + f + ff) * Nc + colb];
        wl[ff][0] = w.x; wl[ff][1] = w.y; wl[ff][2] = w.z; wl[ff][3] = w.w;
      }
#pragma unroll
      for (int i = 0; i < RT; ++i) {
        float4 av = *(const float4*)&at[(rg * RT + i) * KP + f];
        float a0 = av.x, a1 = av.y, a2 = av.z, a3 = av.w;
#pragma unroll
        for (int j = 0; j < 4; ++j) {
          acc[i][j] += a0 * wl[0][j];
          acc[i][j] += a1 * wl[1][j];
          acc[i][j] += a2 * wl[2][j];
          acc[i][j] += a3 * wl[3][j];
        }
      }
    }
    __syncthreads();
  }
#pragma unroll
  for (int i = 0; i < RT; ++i) {
    size_t row = rowb + rg * RT + i;
    float4 o;
    o.x = acc[i][0]; o.y = acc[i][1]; o.z = acc[i][2]; o.w = acc[i][3];
    if (EPI == 1) {
      float4 bv = *(const float4*)&bias[colb];
      o.x = fmaxf(o.x + bv.x, 0.f); o.y = fmaxf(o.y + bv.y, 0.f);
      o.z = fmaxf(o.z + bv.z, 0.f); o.w = fmaxf(o.w + bv.w, 0.f);
    }
    *(float4*)&Cm[row * Nc + colb] = o;
  }
}

// ---------------- MFMA bf16 GEMM: C[M,N] = A[M,K] @ B, A fp32 converted inline ----------------
// tile 64 rows x 128 cols, block 256 (4 waves, wave w: 64 rows x cols [w*32, w*32+32))
// Bswz layout: [k/32][n/16][lane(quad*16+id)*8 + j] where k=kk*32+quad*8+j, n=ntg*16+id
template <int EPI>
__global__ __launch_bounds__(256) void mfma_gemm_k(
    const float* __restrict__ A, const short* __restrict__ Bswz,
    float* __restrict__ C, const float* __restrict__ bias,
    int M, int K, int N) {
  constexpr int RS = 136;
  __shared__ short at[64 * RS];          // 17408 B
  int t = threadIdx.x;
  size_t rowb = (size_t)blockIdx.x * 64;
  int colb = blockIdx.y * 128;
  int w = t >> 6, lane = t & 63, quad = lane >> 4, id = lane & 15;
  f32x4 acc[4][2];
#pragma unroll
  for (int mt = 0; mt < 4; ++mt)
#pragma unroll
    for (int nt = 0; nt < 2; ++nt) acc[mt][nt] = (f32x4){0.f, 0.f, 0.f, 0.f};

  for (int k0 = 0; k0 < K; k0 += 128) {
    // stage A chunk [64 x 128] fp32 -> bf16 LDS
#pragma unroll
    for (int i = 0; i < 4; ++i) {
      int cid = t + i * 256;             // 1024 chunks of 8
      int p = cid >> 4, o8 = (cid & 15) * 8;
      const float* src = &A[(rowb + p) * (size_t)K + k0 + o8];
      float4 v0 = *(const float4*)src;
      float4 v1 = *(const float4*)(src + 4);
      bf16x8 bv;
      bv[0] = f2bf(v0.x); bv[1] = f2bf(v0.y); bv[2] = f2bf(v0.z); bv[3] = f2bf(v0.w);
      bv[4] = f2bf(v1.x); bv[5] = f2bf(v1.y); bv[6] = f2bf(v1.z); bv[7] = f2bf(v1.w);
      *(bf16x8*)&at[p * RS + o8] = bv;
    }
    __syncthreads();
#pragma unroll
    for (int kk = 0; kk < 4; ++kk) {
      bf16x8 af[4], bfr[2];
#pragma unroll
      for (int mt = 0; mt < 4; ++mt)
        af[mt] = *(const bf16x8*)&at[(mt * 16 + id) * RS + kk * 32 + quad * 8];
#pragma unroll
      for (int nt = 0; nt < 2; ++nt) {
        int ntg = (colb >> 4) + w * 2 + nt;
        bfr[nt] = *(const bf16x8*)&Bswz[(((size_t)(k0 >> 5) + kk) * (N >> 4) + ntg) * 512 + lane * 8];
      }
#pragma unroll
      for (int mt = 0; mt < 4; ++mt)
#pragma unroll
        for (int nt = 0; nt < 2; ++nt)
          acc[mt][nt] = __builtin_amdgcn_mfma_f32_16x16x32_bf16(af[mt], bfr[nt], acc[mt][nt], 0, 0, 0);
    }
    __syncthreads();
  }
#pragma unroll
  for (int nt = 0; nt < 2; ++nt) {
    int col = colb + w * 32 + nt * 16 + id;
    float bb = (EPI == 1) ? bias[col] : 0.f;
#pragma unroll
    for (int mt = 0; mt < 4; ++mt) {
#pragma unroll
      for (int reg = 0; reg < 4; ++reg) {
        size_t row = rowb + mt * 16 + quad * 4 + reg;
        float v = acc[mt][nt][reg] + bb;
        if (EPI == 1) v = fmaxf(v, 0.f);
        C[row * (size_t)N + col] = v;
      }
    }
  }
}

// generic B swizzle fp32 -> bf16 fragment order
template <int K, int N>
__global__ void swz_k(const float* __restrict__ B, short* __restrict__ o) {
  int i = blockIdx.x * 256 + threadIdx.x;
  if (i >= K * N) return;
  int n = i % N, k = i / N;
  int kk = k >> 5, quad = (k >> 3) & 3, j = k & 7, ntg = n >> 4, id = n & 15;
  o[(((size_t)kk * (N >> 4)) + ntg) * 512 + (quad * 16 + id) * 8 + j] = f2bf(B[i]);
}

// ---------------- attention coefficients ----------------
template <int HD, int C>
__global__ __launch_bounds__(256) void coef_k(
    const float* __restrict__ h, const float* __restrict__ a_src,
    const float* __restrict__ a_dst, float* __restrict__ es, float* __restrict__ ed) {
  int idx = blockIdx.x * 256 + threadIdx.x;
  if (idx >= Nn * HD) return;
  int n = idx / HD, hd = idx % HD;
  const float* hp = h + (size_t)n * HD * C + hd * C;
  const float* sp = a_src + hd * C;
  const float* dp = a_dst + hd * C;
  float s = 0, d = 0;
  for (int c = 0; c < C; c += 4) {
    float4 v = *(const float4*)(hp + c);
    float4 a = *(const float4*)(sp + c);
    float4 b = *(const float4*)(dp + c);
    s += v.x * a.x + v.y * a.y + v.z * a.z + v.w * a.w;
    d += v.x * b.x + v.y * b.y + v.z * b.z + v.w * b.w;
  }
  es[idx] = s; ed[idx] = d;
}

// ---------------- CSR build ----------------
__global__ void zero_k(int* __restrict__ p, int n) {
  int i = blockIdx.x * 256 + threadIdx.x;
  if (i < n) p[i] = 0;
}

__global__ void count_k(const int* __restrict__ eidx, int* __restrict__ cnt) {
  int i = blockIdx.x * 256 + threadIdx.x;
  if (i >= ET) return;
  int dst = (i < En) ? eidx[En + i] : (i - En);
  atomicAdd(&cnt[dst], 1);
}

__global__ __launch_bounds__(256) void scan_k(int* cnt_cur, int* rowoff) {
  __shared__ int s[256];
  int t = threadIdx.x;
  int loc[16]; int run = 0; int base = t * 16;
#pragma unroll
  for (int i = 0; i < 16; ++i) { loc[i] = run; run += cnt_cur[base + i]; }
  s[t] = run;
  __syncthreads();
  for (int off = 1; off < 256; off <<= 1) {
    int v = (t >= off) ? s[t - off] : 0;
    __syncthreads();
    s[t] += v;
    __syncthreads();
  }
  int offset = (t > 0) ? s[t - 1] : 0;
#pragma unroll
  for (int i = 0; i < 16; ++i) {
    int o = offset + loc[i];
    rowoff[base + i] = o;
    cnt_cur[base + i] = o;
  }
  if (t == 255) rowoff[4096] = s[255];
}

__global__ void scatter_k(const int* __restrict__ eidx, int* __restrict__ cur,
                          int* __restrict__ esrc) {
  int i = blockIdx.x * 256 + threadIdx.x;
  if (i >= ET) return;
  int s, d;
  if (i < En) { s = eidx[i]; d = eidx[En + i]; } else { s = d = i - En; }
  int pos = atomicAdd(&cur[d], 1);
  esrc[pos] = s;
}

// ---------------- GAT softmax-aggregate ----------------
template <int HD, int C, bool RELU>
__global__ __launch_bounds__(256) void gat_agg_k(
    const float* __restrict__ h, const float* __restrict__ es,
    const float* __restrict__ ed, const int* __restrict__ row_off,
    const int* __restrict__ eslist, const float* __restrict__ bias,
    float* __restrict__ xout) {
  constexpr int CAP = 320;
  __shared__ float red[256];
  __shared__ float mxs[HD], dns[HD];
  __shared__ float exc[CAP * HD];
  int n = blockIdx.x, t = threadIdx.x;
  int ro = row_off[n], deg = row_off[n + 1] - ro;
  int hd = t % HD, ei = t / HD;
  constexpr int ES = 256 / HD;
  float edv = ed[n * HD + hd];
  float pm = -3.402823466e38f;
  for (int j = ei; j < deg; j += ES) {
    int s = eslist[ro + j];
    float e = es[s * HD + hd] + edv;
    e = (e > 0.f) ? e : LRELU * e;
    pm = fmaxf(pm, e);
  }
  red[t] = pm;
  __syncthreads();
  for (int off = 128; off >= HD; off >>= 1) {
    if (t < off) red[t] = fmaxf(red[t], red[t + off]);
    __syncthreads();
  }
  if (t < HD) mxs[t] = red[t];
  __syncthreads();
  float mx = mxs[hd];
  float ps = 0.f;
  for (int j = ei; j < deg; j += ES) {
    int s = eslist[ro + j];
    float e = es[s * HD + hd] + edv;
    e = (e > 0.f) ? e : LRELU * e;
    float ex = __expf(e - mx);
    if (j < CAP) exc[j * HD + hd] = ex;
    ps += ex;
  }
  red[t] = ps;
  __syncthreads();
  for (int off = 128; off >= HD; off >>= 1) {
    if (t < off) red[t] += red[t + off];
    __syncthreads();
  }
  if (t < HD) dns[t] = red[t];
  __syncthreads();
  for (int c = t; c < HD * C; c += 256) {
    int hh = c / C;
    float mxh = mxs[hh], edh = ed[n * HD + hh];
    float acc = 0.f;
    for (int j = 0; j < deg; ++j) {
      int s = eslist[ro + j];
      float ex;
      if (j < CAP) ex = exc[j * HD + hh];
      else {
        float e = es[s * HD + hh] + edh;
        e = (e > 0.f) ? e : LRELU * e;
        ex = __expf(e - mxh);
      }
      acc += ex * h[(size_t)s * (HD * C) + c];
    }
    float v = acc / dns[hh] + bias[c];
    if (RELU) v = fmaxf(v, 0.f);
    xout[(size_t)n * (HD * C) + c] = v;
  }
}

// ---------------- bf16 prep kernels ----------------
__global__ void cvt_x2_k(const float* __restrict__ x2, short* __restrict__ x2b) {
  int i = blockIdx.x * 256 + threadIdx.x;
  if (i < Nn * 64) x2b[i] = f2bf(x2[i]);
}

// swizzle rW1[r][k][n] (per-relation K=128,N=256)
__global__ void swz_w1_k(const float* __restrict__ rW1, short* __restrict__ Bswz) {
  int i = blockIdx.x * 256 + threadIdx.x;
  if (i >= 6 * 128 * 256) return;
  int n = i & 255, k = (i >> 8) & 127, r = i >> 15;
  int kk = k >> 5, kq = (k >> 3) & 3, j = k & 7, ntg = n >> 4, id = n & 15;
  size_t dst = (((size_t)r * 4 + kk) * 16 + ntg) * 512 + (kq * 16 + id) * 8 + j;
  Bswz[dst] = f2bf(rW1[i]);
}

// ---------------- relation head: MFMA bf16 ----------------
__global__ __launch_bounds__(256) void rel_head_mfma_k(
    const short* __restrict__ x2b, const int* __restrict__ pidx,
    const short* __restrict__ Bswz, const float* __restrict__ rb1,
    const float* __restrict__ lng, const float* __restrict__ lnb,
    const float* __restrict__ rW2, const float* __restrict__ rb2,
    float* __restrict__ out) {
  constexpr int RS = 136;
  __shared__ short feat[64 * RS];
  __shared__ float part[64 * 8];
  __shared__ float stats[64 * 2];
  int t = threadIdx.x;
  int r = blockIdx.y;
  int pb = blockIdx.x * 64;
#pragma unroll
  for (int i = 0; i < 4; ++i) {
    int cid = t + i * 256;
    int p = cid >> 4, q = cid & 15;
    int half = q >> 3, o8 = (q & 7) * 8;
    int node = pidx[(pb + p) * 2 + half];
    *(bf16x8*)&feat[p * RS + half * 64 + o8] = *(const bf16x8*)&x2b[(size_t)node * 64 + o8];
  }
  __syncthreads();

  int w = t >> 6, lane = t & 63;
  int quad = lane >> 4, id = lane & 15;
  f32x4 acc[4][4];
#pragma unroll
  for (int mt = 0; mt < 4; ++mt)
#pragma unroll
    for (int nt = 0; nt < 4; ++nt) acc[mt][nt] = (f32x4){0.f, 0.f, 0.f, 0.f};

  const short* Bb = Bswz + (size_t)r * 4 * 16 * 512;
#pragma unroll
  for (int kk = 0; kk < 4; ++kk) {
    bf16x8 af[4], bfr[4];
#pragma unroll
    for (int mt = 0; mt < 4; ++mt)
      af[mt] = *(const bf16x8*)&feat[(mt * 16 + id) * RS + kk * 32 + quad * 8];
#pragma unroll
    for (int nt = 0; nt < 4; ++nt)
      bfr[nt] = *(const bf16x8*)&Bb[((size_t)kk * 16 + w * 4 + nt) * 512 + lane * 8];
#pragma unroll
    for (int mt = 0; mt < 4; ++mt)
#pragma unroll
      for (int nt = 0; nt < 4; ++nt)
        acc[mt][nt] = __builtin_amdgcn_mfma_f32_16x16x32_bf16(af[mt], bfr[nt], acc[mt][nt], 0, 0, 0);
  }

  float g[4], bv[4], w2[4], rbl[4];
#pragma unroll
  for (int nt = 0; nt < 4; ++nt) {
    int c = r * 256 + w * 64 + nt * 16 + id;
    g[nt] = lng[c]; bv[nt] = lnb[c]; w2[nt] = rW2[c]; rbl[nt] = rb1[c];
  }
#pragma unroll
  for (int mt = 0; mt < 4; ++mt) {
#pragma unroll
    for (int reg = 0; reg < 4; ++reg) {
      float s1 = 0.f, s2 = 0.f;
#pragma unroll
      for (int nt = 0; nt < 4; ++nt) {
        float v = acc[mt][nt][reg] + rbl[nt];
        acc[mt][nt][reg] = v;
        s1 += v; s2 += v * v;
      }
#pragma unroll
      for (int off = 1; off < 16; off <<= 1) {
        s1 += __shfl_xor(s1, off, 64);
        s2 += __shfl_xor(s2, off, 64);
      }
      if (id == 0) {
        int row = mt * 16 + quad * 4 + reg;
        part[row * 8 + w] = s1;
        part[row * 8 + 4 + w] = s2;
      }
    }
  }
  __syncthreads();
  if (t < 64) {
    float s1 = part[t * 8 + 0] + part[t * 8 + 1] + part[t * 8 + 2] + part[t * 8 + 3];
    float s2 = part[t * 8 + 4] + part[t * 8 + 5] + part[t * 8 + 6] + part[t * 8 + 7];
    float mu = s1 * (1.f / 256.f);
    float var = s2 * (1.f / 256.f) - mu * mu;
    stats[t * 2] = mu;
    stats[t * 2 + 1] = rsqrtf(var + 1e-5f);
  }
  __syncthreads();
#pragma unroll
  for (int mt = 0; mt < 4; ++mt) {
#pragma unroll
    for (int reg = 0; reg < 4; ++reg) {
      int row = mt * 16 + quad * 4 + reg;
      float mu = stats[row * 2], rs = stats[row * 2 + 1];
      float pv = 0.f;
#pragma unroll
      for (int nt = 0; nt < 4; ++nt) {
        float v = (acc[mt][nt][reg] - mu) * rs * g[nt] + bv[nt];
        v = fmaxf(v, 0.f);
        pv += v * w2[nt];
      }
#pragma unroll
      for (int off = 1; off < 16; off <<= 1) pv += __shfl_xor(pv, off, 64);
      if (id == 0) part[row * 8 + w] = pv;
    }
  }
  __syncthreads();
  if (t < 64)
    out[(size_t)r * Pn + pb + t] =
        part[t * 8 + 0] + part[t * 8 + 1] + part[t * 8 + 2] + part[t * 8 + 3] + rb2[r];
}

// ---------------- NER second layer ----------------
__global__ __launch_bounds__(256) void ner2_k(
    const float* __restrict__ hid, const float* __restrict__ W2,
    const float* __restrict__ b2, float* __restrict__ out) {
  __shared__ float s[16 * 257];
  int t = threadIdx.x;
  int rowb = blockIdx.x * 16;
#pragma unroll
  for (int i = 0; i < 4; ++i) {
    int cid = t + i * 256;
    int r = cid >> 6;
    int c4 = (cid & 63) * 4;
    *(float4*)&s[r * 257 + c4] = *(const float4*)&hid[(size_t)(rowb + r) * 256 + c4];
  }
  __syncthreads();
  int r = t & 15, j = t >> 4;
  if (j < 9) {
    float a = 0.f;
    for (int k = 0; k < 256; ++k) a += s[r * 257 + k] * W2[k * 9 + j];
    out[(size_t)(rowb + r) * 9 + j] = a + b2[j];
  }
}

extern "C" void kernel_launch(void* const* d_in, const int* in_sizes, int n_in,
                              void* d_out, int out_size, void* d_ws, size_t ws_size,
                              hipStream_t stream) {
  const float* seq = (const float*)d_in[0];
  const int* est = (const int*)d_in[1];
  const int* eln = (const int*)d_in[2];
  const int* ebt = (const int*)d_in[3];
  const int* eidx = (const int*)d_in[4];
  const int* pidx = (const int*)d_in[5];
  const float* W1 = (const float*)d_in[6];
  const float* as1 = (const float*)d_in[7];
  const float* ad1 = (const float*)d_in[8];
  const float* b1 = (const float*)d_in[9];
  const float* W2 = (const float*)d_in[10];
  const float* as2 = (const float*)d_in[11];
  const float* ad2 = (const float*)d_in[12];
  const float* b2 = (const float*)d_in[13];
  const float* rW1 = (const float*)d_in[14];
  const float* rb1 = (const float*)d_in[15];
  const float* lng = (const float*)d_in[16];
  const float* lnb = (const float*)d_in[17];
  const float* rW2 = (const float*)d_in[18];
  const float* rb2 = (const float*)d_in[19];
  const float* nW1 = (const float*)d_in[20];
  const float* nb1 = (const float*)d_in[21];
  const float* nW2 = (const float*)d_in[22];
  const float* nb2 = (const float*)d_in[23];
  float* out = (float*)d_out;
  float* ws = (float*)d_ws;

  float* x0 = ws + OFF_X0;
  short* x2b = (short*)(ws + OFF_X2B);
  short* bsw = (short*)(ws + OFF_BSW);
  float* h1 = ws + OFF_H1;
  float* x1 = ws + OFF_X1;
  float* h2 = ws + OFF_H2;
  float* x2 = ws + OFF_X2;
  float* es1 = ws + OFF_ES1;
  float* ed1 = ws + OFF_ED1;
  float* es2 = ws + OFF_ES2;
  float* ed2 = ws + OFF_ED2;
  int* rowoff = (int*)(ws + OFF_ROW);
  int* cur = (int*)(ws + OFF_CUR);
  int* edg = (int*)(ws + OFF_EDG);
  short* w1s = (short*)(ws + OFF_W1S);
  short* nw1s = (short*)(ws + OFF_NW1S);
  float* nhid = ws + OFF_X0;  // reuse x0 region after GAT1 GEMM is done

  // CSR build + weight swizzles (independent of features)
  zero_k<<<16, 256, 0, stream>>>(cur, Nn);
  count_k<<<(ET + 255) / 256, 256, 0, stream>>>(eidx, cur);
  scan_k<<<1, 256, 0, stream>>>(cur, rowoff);
  scatter_k<<<(ET + 255) / 256, 256, 0, stream>>>(eidx, cur, edg);
  swz_w1_k<<<(6 * 128 * 256) / 256, 256, 0, stream>>>(rW1, bsw);
  swz_k<768, 512><<<(768 * 512 + 255) / 256, 256, 0, stream>>>(W1, w1s);
  swz_k<768, 256><<<(768 * 256 + 255) / 256, 256, 0, stream>>>(nW1, nw1s);

  // entity features
  span_pool_k<<<Nn * (Hn / 4) / 256, 256, 0, stream>>>(seq, est, eln, ebt, x0);

  // GAT layer 1 (MFMA bf16)
  mfma_gemm_k<0><<<dim3(Nn / 64, 512 / 128), 256, 0, stream>>>(x0, w1s, h1, nullptr, Nn, Hn, 512);
  coef_k<4, 128><<<(Nn * 4) / 256, 256, 0, stream>>>(h1, as1, ad1, es1, ed1);
  gat_agg_k<4, 128, true><<<Nn, 256, 0, stream>>>(h1, es1, ed1, rowoff, edg, b1, x1);

  // GAT layer 2 (fp32, small)
  gemm_k<64, 4, 0><<<dim3(Nn / 64, 1), 256, 0, stream>>>(x1, W2, h2, nullptr, Nn, 512, 64);
  coef_k<1, 64><<<(Nn + 255) / 256, 256, 0, stream>>>(h2, as2, ad2, es2, ed2);
  gat_agg_k<1, 64, false><<<Nn, 256, 0, stream>>>(h2, es2, ed2, rowoff, edg, b2, x2);
  cvt_x2_k<<<(Nn * 64) / 256, 256, 0, stream>>>(x2, x2b);

  // relation head (MFMA bf16) -> out[147456 ..]
  rel_head_mfma_k<<<dim3(Pn / 64, 6), 256, 0, stream>>>(x2b, pidx, bsw, rb1, lng, lnb, rW2, rb2,
                                                        out + (size_t)Bn * Sn * 9);

  // NER head (MFMA bf16) -> out[0 .. 147455]
  mfma_gemm_k<1><<<dim3((Bn * Sn) / 64, 256 / 128), 256, 0, stream>>>(seq, nw1s, nhid, nb1, Bn * Sn, Hn, 256);
  ner2_k<<<(Bn * Sn) / 16, 256, 0, stream>>>(nhid, nW2, nb2, out);
}

// Round 4
// 375.627 us; speedup vs baseline: 2.9239x; 1.3579x over previous
//
#include <hip/hip_runtime.h>
#include <math.h>

#define LRELU 0.2f

constexpr int Bn = 32, Sn = 512, Hn = 768, Nn = 4096, En = 131072, Pn = 65536;
constexpr int ET = En + Nn;  // edges + self loops

typedef __attribute__((ext_vector_type(8))) short bf16x8;
typedef __attribute__((ext_vector_type(4))) float f32x4;

// ---------- workspace layout (float offsets) ----------
// UV bf16 [4096 x 3072] lives at 0..6291456, overlapping dead x0 (after GAT1)
// and dead h1 (after agg1); nhid (0..4194304) overwrites UV after pair kernel.
constexpr size_t OFF_X0  = 0;                      // 4096*768 fp32 (span feats)
constexpr size_t OFF_UV  = 0;                      // 4096*3072 bf16 = 6291456 float-slots
constexpr size_t OFF_H1  = 4194304;                // 4096*512
constexpr size_t OFF_X1  = OFF_H1  + 2097152;      // 4096*512
constexpr size_t OFF_H2  = OFF_X1  + 2097152;      // 4096*64; later UV-weight swizzle (98304 fits)
constexpr size_t OFF_X2  = OFF_H2  + 262144;       // 4096*64
constexpr size_t OFF_ES1 = OFF_X2  + 262144;       // 4096*4
constexpr size_t OFF_ED1 = OFF_ES1 + 16384;
constexpr size_t OFF_ES2 = OFF_ED1 + 16384;        // 4096
constexpr size_t OFF_ED2 = OFF_ES2 + 4096;
constexpr size_t OFF_ROW = OFF_ED2 + 4096;         // int[4097]
constexpr size_t OFF_CUR = OFF_ROW + 4104;         // int[4096]
constexpr size_t OFF_EDG = OFF_CUR + 4096;         // int[135168]
constexpr size_t OFF_W1S = OFF_EDG + 135168;       // 768*512 bf16 = 196608 floats; later W2 swz (16384)
constexpr size_t OFF_NW1S = OFF_W1S + 196608;      // 768*256 bf16 = 98304 floats
// end 9392136 floats (~37.6 MB) — same as proven R3 layout

__device__ __forceinline__ short f2bf(float f) {
  union { float f; unsigned u; } x; x.f = f;
  unsigned r = x.u + 0x7fff + ((x.u >> 16) & 1);   // RNE
  return (short)(r >> 16);
}
__device__ __forceinline__ float bf2f(short s) {
  union { unsigned u; float f; } x;
  x.u = ((unsigned)(unsigned short)s) << 16;
  return x.f;
}

// ---------------- span mean pooling ----------------
__global__ __launch_bounds__(256) void span_pool_k(
    const float* __restrict__ seq, const int* __restrict__ est,
    const int* __restrict__ eln, const int* __restrict__ ebt,
    float* __restrict__ x0) {
  int idx = blockIdx.x * 256 + threadIdx.x;
  if (idx >= Nn * (Hn / 4)) return;
  int e = idx / (Hn / 4);
  int c = (idx % (Hn / 4)) * 4;
  int s0 = est[e], L = eln[e] + 1, b = ebt[e];
  const float* p = seq + ((size_t)b * Sn + s0) * Hn + c;
  float ax = 0, ay = 0, az = 0, aw = 0;
  for (int i = 0; i < L; ++i) {
    float4 v = *(const float4*)(p + (size_t)i * Hn);
    ax += v.x; ay += v.y; az += v.z; aw += v.w;
  }
  float inv = 1.0f / (float)L;
  float4 o; o.x = ax * inv; o.y = ay * inv; o.z = az * inv; o.w = aw * inv;
  *(float4*)&x0[(size_t)e * Hn + c] = o;
}

// ---------------- MFMA bf16 GEMM: C[M,N] = A[M,K] @ Bswz ----------------
// tile 64 rows x (64*NTW) cols, block 256 (4 waves; wave w: 64 rows x NTW 16-col tiles)
// A fp32, converted to bf16 during LDS staging. KC = K-chunk (128 or 64).
// Bswz: [k/32][n/16][(quad*16+id)*8 + j], k = kk*32+quad*8+j, n = ntg*16+id.
// EPI: 0 = fp32 store; 1 = +bias, relu, fp32 store; 2 = bf16 store (no bias)
template <int EPI, int NTW, int KC>
__global__ __launch_bounds__(256) void mfma_gemm_k(
    const float* __restrict__ A, const short* __restrict__ Bswz,
    float* __restrict__ C, const float* __restrict__ bias,
    int M, int K, int N) {
  constexpr int RS = KC + 8;
  __shared__ short at[64 * RS];
  int t = threadIdx.x;
  size_t rowb = (size_t)blockIdx.x * 64;
  int colb = blockIdx.y * (64 * NTW);
  int w = t >> 6, lane = t & 63, quad = lane >> 4, id = lane & 15;
  f32x4 acc[4][NTW];
#pragma unroll
  for (int mt = 0; mt < 4; ++mt)
#pragma unroll
    for (int nt = 0; nt < NTW; ++nt) acc[mt][nt] = (f32x4){0.f, 0.f, 0.f, 0.f};

  for (int k0 = 0; k0 < K; k0 += KC) {
    constexpr int CH = 64 * KC / 8 / 256;
#pragma unroll
    for (int i = 0; i < CH; ++i) {
      int cid = t + i * 256;
      int p = cid / (KC / 8), o8 = (cid % (KC / 8)) * 8;
      const float* src = &A[(rowb + p) * (size_t)K + k0 + o8];
      float4 v0 = *(const float4*)src;
      float4 v1 = *(const float4*)(src + 4);
      bf16x8 bv;
      bv[0] = f2bf(v0.x); bv[1] = f2bf(v0.y); bv[2] = f2bf(v0.z); bv[3] = f2bf(v0.w);
      bv[4] = f2bf(v1.x); bv[5] = f2bf(v1.y); bv[6] = f2bf(v1.z); bv[7] = f2bf(v1.w);
      *(bf16x8*)&at[p * RS + o8] = bv;
    }
    __syncthreads();
#pragma unroll
    for (int kk = 0; kk < KC / 32; ++kk) {
      bf16x8 af[4], bfr[NTW];
#pragma unroll
      for (int mt = 0; mt < 4; ++mt)
        af[mt] = *(const bf16x8*)&at[(mt * 16 + id) * RS + kk * 32 + quad * 8];
#pragma unroll
      for (int nt = 0; nt < NTW; ++nt) {
        int ntg = (colb >> 4) + w * NTW + nt;
        bfr[nt] = *(const bf16x8*)&Bswz[(((size_t)(k0 >> 5) + kk) * (N >> 4) + ntg) * 512 + lane * 8];
      }
#pragma unroll
      for (int mt = 0; mt < 4; ++mt)
#pragma unroll
        for (int nt = 0; nt < NTW; ++nt)
          acc[mt][nt] = __builtin_amdgcn_mfma_f32_16x16x32_bf16(af[mt], bfr[nt], acc[mt][nt], 0, 0, 0);
    }
    __syncthreads();
  }
#pragma unroll
  for (int nt = 0; nt < NTW; ++nt) {
    int col = colb + w * (16 * NTW) + nt * 16 + id;
    float bb = (EPI == 1) ? bias[col] : 0.f;
#pragma unroll
    for (int mt = 0; mt < 4; ++mt) {
#pragma unroll
      for (int reg = 0; reg < 4; ++reg) {
        size_t row = rowb + mt * 16 + quad * 4 + reg;
        float v = acc[mt][nt][reg];
        if (EPI == 1) v = fmaxf(v + bb, 0.f);
        if (EPI == 2) ((short*)C)[row * (size_t)N + col] = f2bf(v);
        else          C[row * (size_t)N + col] = v;
      }
    }
  }
}

// generic B swizzle fp32 -> bf16 fragment order
template <int K, int N>
__global__ void swz_k(const float* __restrict__ B, short* __restrict__ o) {
  int i = blockIdx.x * 256 + threadIdx.x;
  if (i >= K * N) return;
  int n = i % N, k = i / N;
  int kk = k >> 5, quad = (k >> 3) & 3, j = k & 7, ntg = n >> 4, id = n & 15;
  o[(((size_t)kk * (N >> 4)) + ntg) * 512 + (quad * 16 + id) * 8 + j] = f2bf(B[i]);
}

// UV-weight swizzle: rW1[r][k][n] (6,128,256) -> combined B [K=64, N=3072]
// combined col c = r*512 + (k>>6)*256 + n, combined k = k & 63
__global__ void swz_uv_k(const float* __restrict__ rW1, short* __restrict__ o) {
  int i = blockIdx.x * 256 + threadIdx.x;
  if (i >= 6 * 128 * 256) return;
  int n = i & 255, k = (i >> 8) & 127, r = i >> 15;
  int c = r * 512 + (k >> 6) * 256 + n;
  int kr = k & 63;
  int kk = kr >> 5, quad = (kr >> 3) & 3, j = kr & 7, ntg = c >> 4, id = c & 15;
  o[(((size_t)kk * 192) + ntg) * 512 + (quad * 16 + id) * 8 + j] = f2bf(rW1[i]);
}

// ---------------- attention coefficients ----------------
template <int HD, int C>
__global__ __launch_bounds__(256) void coef_k(
    const float* __restrict__ h, const float* __restrict__ a_src,
    const float* __restrict__ a_dst, float* __restrict__ es, float* __restrict__ ed) {
  int idx = blockIdx.x * 256 + threadIdx.x;
  if (idx >= Nn * HD) return;
  int n = idx / HD, hd = idx % HD;
  const float* hp = h + (size_t)n * HD * C + hd * C;
  const float* sp = a_src + hd * C;
  const float* dp = a_dst + hd * C;
  float s = 0, d = 0;
  for (int c = 0; c < C; c += 4) {
    float4 v = *(const float4*)(hp + c);
    float4 a = *(const float4*)(sp + c);
    float4 b = *(const float4*)(dp + c);
    s += v.x * a.x + v.y * a.y + v.z * a.z + v.w * a.w;
    d += v.x * b.x + v.y * b.y + v.z * b.z + v.w * b.w;
  }
  es[idx] = s; ed[idx] = d;
}

// ---------------- CSR build ----------------
__global__ void zero_k(int* __restrict__ p, int n) {
  int i = blockIdx.x * 256 + threadIdx.x;
  if (i < n) p[i] = 0;
}

__global__ void count_k(const int* __restrict__ eidx, int* __restrict__ cnt) {
  int i = blockIdx.x * 256 + threadIdx.x;
  if (i >= ET) return;
  int dst = (i < En) ? eidx[En + i] : (i - En);
  atomicAdd(&cnt[dst], 1);
}

__global__ __launch_bounds__(256) void scan_k(int* cnt_cur, int* rowoff) {
  __shared__ int s[256];
  int t = threadIdx.x;
  int loc[16]; int run = 0; int base = t * 16;
#pragma unroll
  for (int i = 0; i < 16; ++i) { loc[i] = run; run += cnt_cur[base + i]; }
  s[t] = run;
  __syncthreads();
  for (int off = 1; off < 256; off <<= 1) {
    int v = (t >= off) ? s[t - off] : 0;
    __syncthreads();
    s[t] += v;
    __syncthreads();
  }
  int offset = (t > 0) ? s[t - 1] : 0;
#pragma unroll
  for (int i = 0; i < 16; ++i) {
    int o = offset + loc[i];
    rowoff[base + i] = o;
    cnt_cur[base + i] = o;
  }
  if (t == 255) rowoff[4096] = s[255];
}

__global__ void scatter_k(const int* __restrict__ eidx, int* __restrict__ cur,
                          int* __restrict__ esrc) {
  int i = blockIdx.x * 256 + threadIdx.x;
  if (i >= ET) return;
  int s, d;
  if (i < En) { s = eidx[i]; d = eidx[En + i]; } else { s = d = i - En; }
  int pos = atomicAdd(&cur[d], 1);
  esrc[pos] = s;
}

// ---------------- GAT softmax-aggregate ----------------
template <int HD, int C, bool RELU>
__global__ __launch_bounds__(256) void gat_agg_k(
    const float* __restrict__ h, const float* __restrict__ es,
    const float* __restrict__ ed, const int* __restrict__ row_off,
    const int* __restrict__ eslist, const float* __restrict__ bias,
    float* __restrict__ xout) {
  constexpr int CAP = 320;
  __shared__ float red[256];
  __shared__ float mxs[HD], dns[HD];
  __shared__ float exc[CAP * HD];
  int n = blockIdx.x, t = threadIdx.x;
  int ro = row_off[n], deg = row_off[n + 1] - ro;
  int hd = t % HD, ei = t / HD;
  constexpr int ES = 256 / HD;
  float edv = ed[n * HD + hd];
  float pm = -3.402823466e38f;
  for (int j = ei; j < deg; j += ES) {
    int s = eslist[ro + j];
    float e = es[s * HD + hd] + edv;
    e = (e > 0.f) ? e : LRELU * e;
    pm = fmaxf(pm, e);
  }
  red[t] = pm;
  __syncthreads();
  for (int off = 128; off >= HD; off >>= 1) {
    if (t < off) red[t] = fmaxf(red[t], red[t + off]);
    __syncthreads();
  }
  if (t < HD) mxs[t] = red[t];
  __syncthreads();
  float mx = mxs[hd];
  float ps = 0.f;
  for (int j = ei; j < deg; j += ES) {
    int s = eslist[ro + j];
    float e = es[s * HD + hd] + edv;
    e = (e > 0.f) ? e : LRELU * e;
    float ex = __expf(e - mx);
    if (j < CAP) exc[j * HD + hd] = ex;
    ps += ex;
  }
  red[t] = ps;
  __syncthreads();
  for (int off = 128; off >= HD; off >>= 1) {
    if (t < off) red[t] += red[t + off];
    __syncthreads();
  }
  if (t < HD) dns[t] = red[t];
  __syncthreads();
  for (int c = t; c < HD * C; c += 256) {
    int hh = c / C;
    float mxh = mxs[hh], edh = ed[n * HD + hh];
    float acc = 0.f;
    for (int j = 0; j < deg; ++j) {
      int s = eslist[ro + j];
      float ex;
      if (j < CAP) ex = exc[j * HD + hh];
      else {
        float e = es[s * HD + hh] + edh;
        e = (e > 0.f) ? e : LRELU * e;
        ex = __expf(e - mxh);
      }
      acc += ex * h[(size_t)s * (HD * C) + c];
    }
    float v = acc / dns[hh] + bias[c];
    if (RELU) v = fmaxf(v, 0.f);
    xout[(size_t)n * (HD * C) + c] = v;
  }
}

// ---------------- pair relation head: out[r,p] from U[i]+V[j] ----------------
// UV bf16 [node][3072]: per node, 6 relations x (U 256 | V 256).
// grid (P/256, 6); block 256 = 4 waves; 16-lane group per pair, 4 pairs/wave/iter.
__global__ __launch_bounds__(256) void pair_rel_k(
    const short* __restrict__ UV, const int* __restrict__ pidx,
    const float* __restrict__ rb1, const float* __restrict__ lng,
    const float* __restrict__ lnb, const float* __restrict__ rW2,
    const float* __restrict__ rb2, float* __restrict__ out) {
  int t = threadIdx.x;
  int r = blockIdx.y;
  int w = t >> 6, lane = t & 63;
  int pg = lane >> 4, l16 = lane & 15;
  float rbl[16], g[16], bb[16], wv[16];
  int cb = r * 256 + l16 * 16;
#pragma unroll
  for (int q = 0; q < 4; ++q) {
    *(float4*)&rbl[q * 4] = *(const float4*)&rb1[cb + q * 4];
    *(float4*)&g[q * 4]   = *(const float4*)&lng[cb + q * 4];
    *(float4*)&bb[q * 4]  = *(const float4*)&lnb[cb + q * 4];
    *(float4*)&wv[q * 4]  = *(const float4*)&rW2[cb + q * 4];
  }
  float rb2v = rb2[r];
  int pbase = blockIdx.x * 256 + w * 64;
  for (int it = 0; it < 16; ++it) {
    int p = pbase + it * 4 + pg;
    int i = pidx[p * 2], j = pidx[p * 2 + 1];
    const short* up = &UV[(size_t)i * 3072 + r * 512 + l16 * 16];
    const short* vp = &UV[(size_t)j * 3072 + r * 512 + 256 + l16 * 16];
    bf16x8 u0 = *(const bf16x8*)up, u1 = *(const bf16x8*)(up + 8);
    bf16x8 v0 = *(const bf16x8*)vp, v1 = *(const bf16x8*)(vp + 8);
    float hv[16], s1 = 0.f, s2 = 0.f;
#pragma unroll
    for (int cc = 0; cc < 8; ++cc) {
      float h = bf2f(u0[cc]) + bf2f(v0[cc]) + rbl[cc];
      hv[cc] = h; s1 += h; s2 += h * h;
    }
#pragma unroll
    for (int cc = 0; cc < 8; ++cc) {
      float h = bf2f(u1[cc]) + bf2f(v1[cc]) + rbl[8 + cc];
      hv[8 + cc] = h; s1 += h; s2 += h * h;
    }
#pragma unroll
    for (int off = 1; off < 16; off <<= 1) {
      s1 += __shfl_xor(s1, off, 64);
      s2 += __shfl_xor(s2, off, 64);
    }
    float mu = s1 * (1.f / 256.f);
    float var = s2 * (1.f / 256.f) - mu * mu;
    float rs = rsqrtf(var + 1e-5f);
    float pv = 0.f;
#pragma unroll
    for (int cc = 0; cc < 16; ++cc) {
      float v = (hv[cc] - mu) * rs * g[cc] + bb[cc];
      v = fmaxf(v, 0.f);
      pv += v * wv[cc];
    }
#pragma unroll
    for (int off = 1; off < 16; off <<= 1) pv += __shfl_xor(pv, off, 64);
    if (l16 == 0) out[(size_t)r * Pn + p] = pv + rb2v;
  }
}

// ---------------- NER second layer ----------------
__global__ __launch_bounds__(256) void ner2_k(
    const float* __restrict__ hid, const float* __restrict__ W2,
    const float* __restrict__ b2, float* __restrict__ out) {
  __shared__ float s[16 * 257];
  int t = threadIdx.x;
  int rowb = blockIdx.x * 16;
#pragma unroll
  for (int i = 0; i < 4; ++i) {
    int cid = t + i * 256;
    int r = cid >> 6;
    int c4 = (cid & 63) * 4;
    *(float4*)&s[r * 257 + c4] = *(const float4*)&hid[(size_t)(rowb + r) * 256 + c4];
  }
  __syncthreads();
  int r = t & 15, j = t >> 4;
  if (j < 9) {
    float a = 0.f;
    for (int k = 0; k < 256; ++k) a += s[r * 257 + k] * W2[k * 9 + j];
    out[(size_t)(rowb + r) * 9 + j] = a + b2[j];
  }
}

extern "C" void kernel_launch(void* const* d_in, const int* in_sizes, int n_in,
                              void* d_out, int out_size, void* d_ws, size_t ws_size,
                              hipStream_t stream) {
  const float* seq = (const float*)d_in[0];
  const int* est = (const int*)d_in[1];
  const int* eln = (const int*)d_in[2];
  const int* ebt = (const int*)d_in[3];
  const int* eidx = (const int*)d_in[4];
  const int* pidx = (const int*)d_in[5];
  const float* W1 = (const float*)d_in[6];
  const float* as1 = (const float*)d_in[7];
  const float* ad1 = (const float*)d_in[8];
  const float* b1 = (const float*)d_in[9];
  const float* W2 = (const float*)d_in[10];
  const float* as2 = (const float*)d_in[11];
  const float* ad2 = (const float*)d_in[12];
  const float* b2 = (const float*)d_in[13];
  const float* rW1 = (const float*)d_in[14];
  const float* rb1 = (const float*)d_in[15];
  const float* lng = (const float*)d_in[16];
  const float* lnb = (const float*)d_in[17];
  const float* rW2 = (const float*)d_in[18];
  const float* rb2 = (const float*)d_in[19];
  const float* nW1 = (const float*)d_in[20];
  const float* nb1 = (const float*)d_in[21];
  const float* nW2 = (const float*)d_in[22];
  const float* nb2 = (const float*)d_in[23];
  float* out = (float*)d_out;
  float* ws = (float*)d_ws;

  float* x0 = ws + OFF_X0;
  short* uv = (short*)(ws + OFF_UV);
  float* h1 = ws + OFF_H1;
  float* x1 = ws + OFF_X1;
  float* h2 = ws + OFF_H2;
  short* uvw = (short*)(ws + OFF_H2);   // after agg2, h2 region reused for UV weights
  float* x2 = ws + OFF_X2;
  float* es1 = ws + OFF_ES1;
  float* ed1 = ws + OFF_ED1;
  float* es2 = ws + OFF_ES2;
  float* ed2 = ws + OFF_ED2;
  int* rowoff = (int*)(ws + OFF_ROW);
  int* cur = (int*)(ws + OFF_CUR);
  int* edg = (int*)(ws + OFF_EDG);
  short* w1s = (short*)(ws + OFF_W1S);
  short* w2s = (short*)(ws + OFF_W1S);  // after GAT1 GEMM, W1S region reused for W2
  short* nw1s = (short*)(ws + OFF_NW1S);
  float* nhid = ws + OFF_X0;            // after pair kernel, reuse as NER hidden

  // CSR build + weight swizzles
  zero_k<<<16, 256, 0, stream>>>(cur, Nn);
  count_k<<<(ET + 255) / 256, 256, 0, stream>>>(eidx, cur);
  scan_k<<<1, 256, 0, stream>>>(cur, rowoff);
  scatter_k<<<(ET + 255) / 256, 256, 0, stream>>>(eidx, cur, edg);
  swz_k<768, 512><<<(768 * 512 + 255) / 256, 256, 0, stream>>>(W1, w1s);
  swz_k<768, 256><<<(768 * 256 + 255) / 256, 256, 0, stream>>>(nW1, nw1s);

  // entity features
  span_pool_k<<<Nn * (Hn / 4) / 256, 256, 0, stream>>>(seq, est, eln, ebt, x0);

  // GAT layer 1 (MFMA bf16)
  mfma_gemm_k<0, 2, 128><<<dim3(Nn / 64, 512 / 128), 256, 0, stream>>>(x0, w1s, h1, nullptr, Nn, Hn, 512);
  swz_k<512, 64><<<(512 * 64 + 255) / 256, 256, 0, stream>>>(W2, w2s);  // reuses W1S region (w1s dead)
  coef_k<4, 128><<<(Nn * 4) / 256, 256, 0, stream>>>(h1, as1, ad1, es1, ed1);
  gat_agg_k<4, 128, true><<<Nn, 256, 0, stream>>>(h1, es1, ed1, rowoff, edg, b1, x1);

  // GAT layer 2 (MFMA bf16, 64-col tile)
  mfma_gemm_k<0, 1, 128><<<dim3(Nn / 64, 1), 256, 0, stream>>>(x1, w2s, h2, nullptr, Nn, 512, 64);
  coef_k<1, 64><<<(Nn + 255) / 256, 256, 0, stream>>>(h2, as2, ad2, es2, ed2);
  gat_agg_k<1, 64, false><<<Nn, 256, 0, stream>>>(h2, es2, ed2, rowoff, edg, b2, x2);

  // relation head: U/V node GEMM (K=64, N=3072, bf16 out) then pair epilogue
  swz_uv_k<<<(6 * 128 * 256) / 256, 256, 0, stream>>>(rW1, uvw);       // reuses h2 region (dead)
  mfma_gemm_k<2, 2, 64><<<dim3(Nn / 64, 3072 / 128), 256, 0, stream>>>(x2, uvw, (float*)uv, nullptr, Nn, 64, 3072);
  pair_rel_k<<<dim3(Pn / 256, 6), 256, 0, stream>>>(uv, pidx, rb1, lng, lnb, rW2, rb2,
                                                    out + (size_t)Bn * Sn * 9);

  // NER head (MFMA bf16) -> out[0 .. 147455]; nhid overwrites UV (dead)
  mfma_gemm_k<1, 2, 128><<<dim3((Bn * Sn) / 64, 256 / 128), 256, 0, stream>>>(seq, nw1s, nhid, nb1, Bn * Sn, Hn, 256);
  ner2_k<<<(Bn * Sn) / 16, 256, 0, stream>>>(nhid, nW2, nb2, out);
}